// Round 4
// baseline (2800.788 us; speedup 1.0000x reference)
//
#include <hip/hip_runtime.h>
#include <hip/hip_bf16.h>
#include <math.h>

#define D_F   64
#define IN_F  183     // 2*64 + 2*25 + 3 + 1 + 1
#define KS1   6       // layer-1 K tiles: 192 = 6*32 (padded from 183)
#define KS2   8       // layer-2/3 K tiles: 256 = 8*32
#define HID   256
#define XPITCH 200    // u16 per x row: 400B = 25 x 16B, 25%8==1 -> uniform bank spread
#define HPITCH 264    // u16 per h row: 528B = 33 x 16B, 33%8==1
#define BM    64      // pairs per block

typedef unsigned short u16;
typedef __attribute__((ext_vector_type(8))) short bf16x8;
typedef __attribute__((ext_vector_type(4))) float f32x4;

__device__ __forceinline__ u16 f2bf(float v) {
    __hip_bfloat16 h = __float2bfloat16(v);   // RNE
    u16 u; __builtin_memcpy(&u, &h, 2); return u;
}

// ---------------------------------------------------------------------------
// Pack W (K x 256 f32, row-major) into MFMA B-fragment order (bf16):
//   Wp[((ct*KSs + ks)*64 + lane)*8 + j] = W[ks*32 + 8*(lane>>4) + j][ct*16 + (lane&15)]
// ---------------------------------------------------------------------------
__global__ void pack_w_kernel(const float* __restrict__ W, u16* __restrict__ Wp,
                              int K, int KSs)
{
    int g = blockIdx.x * 256 + threadIdx.x;
    int total = 16 * KSs * 64;
    if (g >= total) return;
    int lane = g & 63;
    int ks   = (g >> 6) % KSs;
    int ct   = (g >> 6) / KSs;
    int col  = ct * 16 + (lane & 15);
    int kb   = ks * 32 + 8 * (lane >> 4);
    u16 out[8];
    #pragma unroll
    for (int j = 0; j < 8; ++j) {
        int k = kb + j;
        out[j] = f2bf((k < K) ? W[(size_t)k * HID + col] : 0.0f);
    }
    *(bf16x8*)(Wp + (size_t)g * 8) = *(const bf16x8*)out;
}

// Pack W3 (256 x 3 f32) into a 16-col B fragment (cols 3..15 zero):
//   W3p[(ks*64 + lane)*8 + j] = (lane&15)<3 ? W3[(ks*32+8*(lane>>4)+j)*3 + (lane&15)] : 0
__global__ void pack_w3_kernel(const float* __restrict__ W3, u16* __restrict__ W3p)
{
    int g = blockIdx.x * 256 + threadIdx.x;
    if (g >= KS2 * 64) return;
    int lane = g & 63;
    int ks   = g >> 6;
    int n    = lane & 15;
    int kb   = ks * 32 + 8 * (lane >> 4);
    u16 out[8];
    #pragma unroll
    for (int j = 0; j < 8; ++j)
        out[j] = f2bf((n < 3) ? W3[(size_t)(kb + j) * 3 + n] : 0.0f);
    *(bf16x8*)(W3p + (size_t)g * 8) = *(const bf16x8*)out;
}

// ---------------------------------------------------------------------------
// Pair-block fused MLP. Block = 64 pairs at one fixed t (gridDim.y = T+1).
// Layer-1 GEMM runs ONCE per block (one-hot cols zeroed out of x; the one-hot
// contribution W1[178+k] is added in f32 per k). acc1 held in registers across
// the k-loop. Layers 2 and 3 run per k. Single LDS buffer: x -> h1 -> h2.
// ---------------------------------------------------------------------------
__global__ __launch_bounds__(256, 2)
void mfp_mlp_mfma(const float* __restrict__ features,
                  const float* __restrict__ states,
                  const float* __restrict__ distances,
                  const float* __restrict__ W1,   // f32, for one-hot rows 178..180
                  const u16* __restrict__ W1p, const float* __restrict__ b1,
                  const u16* __restrict__ W2p, const float* __restrict__ b2,
                  const u16* __restrict__ W3p, const float* __restrict__ b3,
                  const int* __restrict__ pairs_i, const int* __restrict__ pairs_j,
                  float* __restrict__ cond,
                  int N, int T1s, int E, int T)
{
    extern __shared__ char smem[];
    u16* xs = (u16*)smem;   // [64][XPITCH]  (layer-1 A)
    u16* hs = (u16*)smem;   // [64][HPITCH]  (h1 then h2; union, barrier-separated)
    __shared__ int   s_pi[BM], s_pj[BM], s_e[BM], s_val[BM];
    __shared__ float s_dist[BM];
    __shared__ float s_log[BM][4];

    const int tid = threadIdx.x;
    const int t   = blockIdx.y;
    const int nk  = (t == 0) ? 1 : 3;

    // ---- per-pair meta ----
    if (tid < BM) {
        int pe = blockIdx.x * BM + tid;
        int valid = (pe < E) ? 1 : 0;
        int e = valid ? pe : 0;
        int pi = pairs_i[e], pj = pairs_j[e];
        s_e[tid] = e; s_val[tid] = valid; s_pi[tid] = pi; s_pj[tid] = pj;
        s_dist[tid] = distances[(long long)pi * N + pj];
    }
    __syncthreads();

    // ---- assemble x rows (bf16), one-hot cols (178..180) zeroed ----
    for (int idx = tid; idx < BM * 32; idx += 256) {     // cols 0..127: features
        int m = idx >> 5;
        int q = idx & 31;
        int src = (q < 16) ? s_pi[m] : s_pj[m];
        int c4  = (q & 15) * 4;
        float4 f = *(const float4*)&features[(size_t)src * D_F + c4];
        int c = ((q < 16) ? 0 : 64) + c4;
        ushort4 o;
        o.x = f2bf(f.x); o.y = f2bf(f.y); o.z = f2bf(f.z); o.w = f2bf(f.w);
        *(ushort4*)(xs + m * XPITCH + c) = o;
    }
    for (int idx = tid; idx < BM * 64; idx += 256) {     // cols 128..191
        int m = idx >> 6;
        int c = 128 + (idx & 63);
        float v;
        if (c < 178) {
            int cc = c - 128;
            int row = (cc < 25) ? s_pi[m] : s_pj[m];
            int c2  = (cc < 25) ? cc : (cc - 25);
            int l = c2 / 5;
            int s = c2 - l * 5;
            int tau = t - 4 + l;
            v = (tau >= 0) ? states[((size_t)row * T1s + tau) * 5 + s] : 0.0f;
        } else if (c == 181) {
            v = s_dist[m];
        } else if (c == 182) {
            v = (t == 0) ? 1.0f : 0.0f;
        } else {
            v = 0.0f;   // one-hot 178..180 and pad 183..191
        }
        xs[m * XPITCH + c] = f2bf(v);
    }
    __syncthreads();

    const int lane = tid & 63;
    const int w    = tid >> 6;     // wave id 0..3
    const int ct0  = w * 4;        // col-tile base (cols 64w .. 64w+63)
    const int lr   = lane & 15;
    const int lg   = lane >> 4;

    // ---- layer 1 (once): acc1 = x @ W1  (held across the k-loop) ----
    f32x4 acc1[4][4];
    #pragma unroll
    for (int a = 0; a < 4; ++a)
        #pragma unroll
        for (int b = 0; b < 4; ++b)
            acc1[a][b] = (f32x4){0.f, 0.f, 0.f, 0.f};

    for (int ks = 0; ks < KS1; ++ks) {
        bf16x8 bfr[4];
        #pragma unroll
        for (int ctl = 0; ctl < 4; ++ctl)
            bfr[ctl] = *(const bf16x8*)(W1p + (((size_t)(ct0 + ctl) * KS1 + ks) * 64 + lane) * 8);
        bf16x8 afr[4];
        #pragma unroll
        for (int rt = 0; rt < 4; ++rt)
            afr[rt] = *(const bf16x8*)(xs + (rt * 16 + lr) * XPITCH + ks * 32 + 8 * lg);
        #pragma unroll
        for (int rt = 0; rt < 4; ++rt)
            #pragma unroll
            for (int ctl = 0; ctl < 4; ++ctl)
                acc1[rt][ctl] = __builtin_amdgcn_mfma_f32_16x16x32_bf16(afr[rt], bfr[ctl], acc1[rt][ctl], 0, 0, 0);
    }

    // per-lane column constants
    float b1v[4], b2v[4], w1oh[3][4];
    #pragma unroll
    for (int ctl = 0; ctl < 4; ++ctl) {
        int col = (ct0 + ctl) * 16 + lr;
        b1v[ctl] = b1[col];
        b2v[ctl] = b2[col];
        #pragma unroll
        for (int k3 = 0; k3 < 3; ++k3)
            w1oh[k3][ctl] = W1[(size_t)(178 + k3) * HID + col];
    }
    const float b30 = b3[0], b31 = b3[1], b32 = b3[2];

    // ---- k-loop ----
    for (int k = 0; k < nk; ++k) {
        __syncthreads();   // xs reads (k=0) / previous k's hs+s_log reads done

        // write h1_k = relu(acc1 + b1 + W1[178+k])
        #pragma unroll
        for (int rt = 0; rt < 4; ++rt)
            #pragma unroll
            for (int ctl = 0; ctl < 4; ++ctl)
                #pragma unroll
                for (int r = 0; r < 4; ++r) {
                    float h = fmaxf(acc1[rt][ctl][r] + b1v[ctl] + w1oh[k][ctl], 0.0f);
                    hs[(rt * 16 + 4 * lg + r) * HPITCH + (ct0 + ctl) * 16 + lr] = f2bf(h);
                }
        __syncthreads();

        // layer 2: acc2 = h1 @ W2
        f32x4 acc2[4][4];
        #pragma unroll
        for (int a = 0; a < 4; ++a)
            #pragma unroll
            for (int b = 0; b < 4; ++b)
                acc2[a][b] = (f32x4){0.f, 0.f, 0.f, 0.f};

        for (int ks = 0; ks < KS2; ++ks) {
            bf16x8 bfr[4];
            #pragma unroll
            for (int ctl = 0; ctl < 4; ++ctl)
                bfr[ctl] = *(const bf16x8*)(W2p + (((size_t)(ct0 + ctl) * KS2 + ks) * 64 + lane) * 8);
            bf16x8 afr[4];
            #pragma unroll
            for (int rt = 0; rt < 4; ++rt)
                afr[rt] = *(const bf16x8*)(hs + (rt * 16 + lr) * HPITCH + ks * 32 + 8 * lg);
            #pragma unroll
            for (int rt = 0; rt < 4; ++rt)
                #pragma unroll
                for (int ctl = 0; ctl < 4; ++ctl)
                    acc2[rt][ctl] = __builtin_amdgcn_mfma_f32_16x16x32_bf16(afr[rt], bfr[ctl], acc2[rt][ctl], 0, 0, 0);
        }
        __syncthreads();   // all h1 fragment reads done

        // write h2 = relu(acc2 + b2) over the same buffer
        #pragma unroll
        for (int rt = 0; rt < 4; ++rt)
            #pragma unroll
            for (int ctl = 0; ctl < 4; ++ctl)
                #pragma unroll
                for (int r = 0; r < 4; ++r) {
                    float g = fmaxf(acc2[rt][ctl][r] + b2v[ctl], 0.0f);
                    hs[(rt * 16 + 4 * lg + r) * HPITCH + (ct0 + ctl) * 16 + lr] = f2bf(g);
                }
        __syncthreads();

        // layer 3 via MFMA: wave w computes rows 16w..16w+15, logits in cols 0..2
        f32x4 acc3 = (f32x4){0.f, 0.f, 0.f, 0.f};
        for (int ks = 0; ks < KS2; ++ks) {
            bf16x8 afr = *(const bf16x8*)(hs + (16 * w + lr) * HPITCH + ks * 32 + 8 * lg);
            bf16x8 bfr = *(const bf16x8*)(W3p + ((size_t)(ks * 64 + lane)) * 8);
            acc3 = __builtin_amdgcn_mfma_f32_16x16x32_bf16(afr, bfr, acc3, 0, 0, 0);
        }
        if (lr < 3) {
            #pragma unroll
            for (int r = 0; r < 4; ++r)
                s_log[16 * w + 4 * lg + r][lr] = acc3[r];
        }
        __syncthreads();

        // softmax + write (one thread per pair-row)
        if (tid < BM && s_val[tid]) {
            float l0 = s_log[tid][0] + b30;
            float l1 = s_log[tid][1] + b31;
            float l2 = s_log[tid][2] + b32;
            float mx = fmaxf(l0, fmaxf(l1, l2));
            float e0 = expf(l0 - mx), e1 = expf(l1 - mx), e2 = expf(l2 - mx);
            float inv = 1.0f / (e0 + e1 + e2);
            float p0 = e0 * inv, p1 = e1 * inv, p2 = e2 * inv;
            size_t base = ((size_t)t * E + s_e[tid]) * 9;
            if (t == 0) {
                #pragma unroll
                for (int kb = 0; kb < 3; ++kb) {
                    cond[base + kb * 3 + 0] = p0;
                    cond[base + kb * 3 + 1] = p1;
                    cond[base + kb * 3 + 2] = p2;
                }
            } else {
                cond[base + k * 3 + 0] = p0;
                cond[base + k * 3 + 1] = p1;
                cond[base + k * 3 + 2] = p2;
            }
        }
    }
}

// ---------------------------------------------------------------------------
// Marginal chain: m_t = m_{t-1} @ cond[t]
// ---------------------------------------------------------------------------
__global__ __launch_bounds__(256)
void mfp_marg_kernel(const float* __restrict__ cond,
                     float* __restrict__ marg,
                     int E, int T)
{
    int e = blockIdx.x * 256 + threadIdx.x;
    if (e >= E) return;
    const float* c0 = &cond[(size_t)e * 9];
    float m0 = c0[0], m1 = c0[1], m2 = c0[2];
    marg[(size_t)e * 3 + 0] = m0;
    marg[(size_t)e * 3 + 1] = m1;
    marg[(size_t)e * 3 + 2] = m2;
    for (int t = 1; t <= T; ++t) {
        const float* c9 = &cond[((size_t)t * E + e) * 9];
        float n0 = m0 * c9[0] + m1 * c9[3] + m2 * c9[6];
        float n1 = m0 * c9[1] + m1 * c9[4] + m2 * c9[7];
        float n2 = m0 * c9[2] + m1 * c9[5] + m2 * c9[8];
        m0 = n0; m1 = n1; m2 = n2;
        float* mo = &marg[((size_t)t * E + e) * 3];
        mo[0] = m0; mo[1] = m1; mo[2] = m2;
    }
}

// ---------------------------------------------------------------------------
extern "C" void kernel_launch(void* const* d_in, const int* in_sizes, int n_in,
                              void* d_out, int out_size, void* d_ws, size_t ws_size,
                              hipStream_t stream) {
    const float* features  = (const float*)d_in[0];
    const float* states    = (const float*)d_in[1];
    const float* distances = (const float*)d_in[2];
    const float* W1 = (const float*)d_in[3];
    const float* b1 = (const float*)d_in[4];
    const float* W2 = (const float*)d_in[5];
    const float* b2 = (const float*)d_in[6];
    const float* W3 = (const float*)d_in[7];
    const float* b3 = (const float*)d_in[8];
    const int* pairs_i = (const int*)d_in[9];
    const int* pairs_j = (const int*)d_in[10];

    const int N   = in_sizes[0] / D_F;             // 2000
    const int T1s = in_sizes[1] / (N * 5);         // 11
    const int E   = in_sizes[9];                   // 100000
    const int T   = out_size / (12 * E) - 1;       // 10

    float* cond = (float*)d_out;                            // (T+1, E, 3, 3)
    float* marg = (float*)d_out + (size_t)(T + 1) * E * 9;  // (T+1, E, 3)

    u16* W1p = (u16*)d_ws;                                  // 16*KS1*64*8 elems
    u16* W2p = W1p + 16 * KS1 * 64 * 8;                     // 16*KS2*64*8 elems
    u16* W3p = W2p + 16 * KS2 * 64 * 8;                     // KS2*64*8 elems

    {
        int g1 = 16 * KS1 * 64;
        int g2 = 16 * KS2 * 64;
        int g3 = KS2 * 64;
        pack_w_kernel<<<(g1 + 255) / 256, 256, 0, stream>>>(W1, W1p, IN_F, KS1);
        pack_w_kernel<<<(g2 + 255) / 256, 256, 0, stream>>>(W2, W2p, HID, KS2);
        pack_w3_kernel<<<(g3 + 255) / 256, 256, 0, stream>>>(W3, W3p);
    }

    dim3 grid((E + BM - 1) / BM, T + 1);
    const size_t lds_bytes = (size_t)BM * HPITCH * sizeof(u16);   // 33792 B

    mfp_mlp_mfma<<<grid, 256, lds_bytes, stream>>>(
        features, states, distances, W1, W1p, b1, W2p, b2, W3p, b3,
        pairs_i, pairs_j, cond, N, T1s, E, T);

    mfp_marg_kernel<<<(E + 255) / 256, 256, 0, stream>>>(cond, marg, E, T);
}

// Round 5
// 1345.933 us; speedup vs baseline: 2.0809x; 2.0809x over previous
//
#include <hip/hip_runtime.h>
#include <hip/hip_bf16.h>
#include <math.h>

#define D_F   64
#define IN_F  183     // 2*64 + 2*25 + 3 + 1 + 1
#define KS1   6       // layer-1 K tiles: 192 = 6*32 (padded from 183)
#define KS2   8       // layer-2/3 K tiles: 256 = 8*32
#define HID   256
#define XPITCH 200    // u16 per x row: 400B = 25 x 16B, 25%8==1 -> uniform bank spread
#define HPITCH 264    // u16 per h row: 528B = 33 x 16B, 33%8==1
#define BM    64      // pairs per block

typedef unsigned short u16;
typedef __attribute__((ext_vector_type(8))) short bf16x8;
typedef __attribute__((ext_vector_type(4))) float f32x4;

__device__ __forceinline__ u16 f2bf(float v) {
    __hip_bfloat16 h = __float2bfloat16(v);   // RNE
    u16 u; __builtin_memcpy(&u, &h, 2); return u;
}

// ---------------------------------------------------------------------------
// Pack W (K x 256 f32, row-major) into MFMA B-fragment order (bf16):
//   Wp[((ct*KSs + ks)*64 + lane)*8 + j] = W[ks*32 + 8*(lane>>4) + j][ct*16 + (lane&15)]
// ---------------------------------------------------------------------------
__global__ void pack_w_kernel(const float* __restrict__ W, u16* __restrict__ Wp,
                              int K, int KSs)
{
    int g = blockIdx.x * 256 + threadIdx.x;
    int total = 16 * KSs * 64;
    if (g >= total) return;
    int lane = g & 63;
    int ks   = (g >> 6) % KSs;
    int ct   = (g >> 6) / KSs;
    int col  = ct * 16 + (lane & 15);
    int kb   = ks * 32 + 8 * (lane >> 4);
    u16 out[8];
    #pragma unroll
    for (int j = 0; j < 8; ++j) {
        int k = kb + j;
        out[j] = f2bf((k < K) ? W[(size_t)k * HID + col] : 0.0f);
    }
    *(bf16x8*)(Wp + (size_t)g * 8) = *(const bf16x8*)out;
}

// Pack W3 (256 x 3 f32) into a 16-col B fragment (cols 3..15 zero)
__global__ void pack_w3_kernel(const float* __restrict__ W3, u16* __restrict__ W3p)
{
    int g = blockIdx.x * 256 + threadIdx.x;
    if (g >= KS2 * 64) return;
    int lane = g & 63;
    int ks   = g >> 6;
    int n    = lane & 15;
    int kb   = ks * 32 + 8 * (lane >> 4);
    u16 out[8];
    #pragma unroll
    for (int j = 0; j < 8; ++j)
        out[j] = f2bf((n < 3) ? W3[(size_t)(kb + j) * 3 + n] : 0.0f);
    *(bf16x8*)(W3p + (size_t)g * 8) = *(const bf16x8*)out;
}

// ---------------------------------------------------------------------------
// Pair-block fused MLP. Block = 64 pairs at one fixed t (gridDim.y = T+1).
// Layer-1 GEMM runs ONCE per block; acc1 held in registers across the k-loop.
// NOTE: no min-waves launch bound — acc1(64) + acc2(64) + fragments must fit
// in VGPRs without spilling (round-4's __launch_bounds__(256,2) capped VGPR at
// 128 and spilled acc1 to scratch: FETCH_SIZE 184MB -> 2.6GB, 2.5x slowdown).
// ---------------------------------------------------------------------------
__global__ __launch_bounds__(256)
void mfp_mlp_mfma(const float* __restrict__ features,
                  const float* __restrict__ states,
                  const float* __restrict__ distances,
                  const float* __restrict__ W1,   // f32, for one-hot rows 178..180
                  const u16* __restrict__ W1p, const float* __restrict__ b1,
                  const u16* __restrict__ W2p, const float* __restrict__ b2,
                  const u16* __restrict__ W3p, const float* __restrict__ b3,
                  const int* __restrict__ pairs_i, const int* __restrict__ pairs_j,
                  float* __restrict__ cond,
                  int N, int T1s, int E, int T)
{
    extern __shared__ char smem[];
    u16* xs = (u16*)smem;   // [64][XPITCH]  (layer-1 A)
    u16* hs = (u16*)smem;   // [64][HPITCH]  (h1 then h2; union, barrier-separated)
    __shared__ int   s_pi[BM], s_pj[BM], s_e[BM], s_val[BM];
    __shared__ float s_dist[BM];
    __shared__ float s_log[BM][4];

    const int tid = threadIdx.x;
    const int t   = blockIdx.y;
    const int nk  = (t == 0) ? 1 : 3;

    // ---- per-pair meta ----
    if (tid < BM) {
        int pe = blockIdx.x * BM + tid;
        int valid = (pe < E) ? 1 : 0;
        int e = valid ? pe : 0;
        int pi = pairs_i[e], pj = pairs_j[e];
        s_e[tid] = e; s_val[tid] = valid; s_pi[tid] = pi; s_pj[tid] = pj;
        s_dist[tid] = distances[(long long)pi * N + pj];
    }
    __syncthreads();

    // ---- assemble x rows (bf16), one-hot cols (178..180) zeroed ----
    for (int idx = tid; idx < BM * 32; idx += 256) {     // cols 0..127: features
        int m = idx >> 5;
        int q = idx & 31;
        int src = (q < 16) ? s_pi[m] : s_pj[m];
        int c4  = (q & 15) * 4;
        float4 f = *(const float4*)&features[(size_t)src * D_F + c4];
        int c = ((q < 16) ? 0 : 64) + c4;
        ushort4 o;
        o.x = f2bf(f.x); o.y = f2bf(f.y); o.z = f2bf(f.z); o.w = f2bf(f.w);
        *(ushort4*)(xs + m * XPITCH + c) = o;
    }
    for (int idx = tid; idx < BM * 64; idx += 256) {     // cols 128..191
        int m = idx >> 6;
        int c = 128 + (idx & 63);
        float v;
        if (c < 178) {
            int cc = c - 128;
            int row = (cc < 25) ? s_pi[m] : s_pj[m];
            int c2  = (cc < 25) ? cc : (cc - 25);
            int l = c2 / 5;
            int s = c2 - l * 5;
            int tau = t - 4 + l;
            v = (tau >= 0) ? states[((size_t)row * T1s + tau) * 5 + s] : 0.0f;
        } else if (c == 181) {
            v = s_dist[m];
        } else if (c == 182) {
            v = (t == 0) ? 1.0f : 0.0f;
        } else {
            v = 0.0f;   // one-hot 178..180 and pad 183..191
        }
        xs[m * XPITCH + c] = f2bf(v);
    }
    __syncthreads();

    const int lane = tid & 63;
    const int w    = tid >> 6;     // wave id 0..3
    const int ct0  = w * 4;        // col-tile base (cols 64w .. 64w+63)
    const int lr   = lane & 15;
    const int lg   = lane >> 4;

    // ---- layer 1 (once): acc1 = x @ W1  (held across the k-loop) ----
    f32x4 acc1[4][4];
    #pragma unroll
    for (int a = 0; a < 4; ++a)
        #pragma unroll
        for (int b = 0; b < 4; ++b)
            acc1[a][b] = (f32x4){0.f, 0.f, 0.f, 0.f};

    for (int ks = 0; ks < KS1; ++ks) {
        bf16x8 bfr[4];
        #pragma unroll
        for (int ctl = 0; ctl < 4; ++ctl)
            bfr[ctl] = *(const bf16x8*)(W1p + (((size_t)(ct0 + ctl) * KS1 + ks) * 64 + lane) * 8);
        bf16x8 afr[4];
        #pragma unroll
        for (int rt = 0; rt < 4; ++rt)
            afr[rt] = *(const bf16x8*)(xs + (rt * 16 + lr) * XPITCH + ks * 32 + 8 * lg);
        #pragma unroll
        for (int rt = 0; rt < 4; ++rt)
            #pragma unroll
            for (int ctl = 0; ctl < 4; ++ctl)
                acc1[rt][ctl] = __builtin_amdgcn_mfma_f32_16x16x32_bf16(afr[rt], bfr[ctl], acc1[rt][ctl], 0, 0, 0);
    }

    // per-lane column constants
    float b1v[4], b2v[4], w1oh[3][4];
    #pragma unroll
    for (int ctl = 0; ctl < 4; ++ctl) {
        int col = (ct0 + ctl) * 16 + lr;
        b1v[ctl] = b1[col];
        b2v[ctl] = b2[col];
        #pragma unroll
        for (int k3 = 0; k3 < 3; ++k3)
            w1oh[k3][ctl] = W1[(size_t)(178 + k3) * HID + col];
    }
    const float b30 = b3[0], b31 = b3[1], b32 = b3[2];

    // ---- k-loop ----
    for (int k = 0; k < nk; ++k) {
        __syncthreads();   // xs reads (k=0) / previous k's hs+s_log reads done

        // write h1_k = relu(acc1 + b1 + W1[178+k])
        #pragma unroll
        for (int rt = 0; rt < 4; ++rt)
            #pragma unroll
            for (int ctl = 0; ctl < 4; ++ctl)
                #pragma unroll
                for (int r = 0; r < 4; ++r) {
                    float h = fmaxf(acc1[rt][ctl][r] + b1v[ctl] + w1oh[k][ctl], 0.0f);
                    hs[(rt * 16 + 4 * lg + r) * HPITCH + (ct0 + ctl) * 16 + lr] = f2bf(h);
                }
        __syncthreads();

        // layer 2: acc2 = h1 @ W2
        f32x4 acc2[4][4];
        #pragma unroll
        for (int a = 0; a < 4; ++a)
            #pragma unroll
            for (int b = 0; b < 4; ++b)
                acc2[a][b] = (f32x4){0.f, 0.f, 0.f, 0.f};

        for (int ks = 0; ks < KS2; ++ks) {
            bf16x8 bfr[4];
            #pragma unroll
            for (int ctl = 0; ctl < 4; ++ctl)
                bfr[ctl] = *(const bf16x8*)(W2p + (((size_t)(ct0 + ctl) * KS2 + ks) * 64 + lane) * 8);
            bf16x8 afr[4];
            #pragma unroll
            for (int rt = 0; rt < 4; ++rt)
                afr[rt] = *(const bf16x8*)(hs + (rt * 16 + lr) * HPITCH + ks * 32 + 8 * lg);
            #pragma unroll
            for (int rt = 0; rt < 4; ++rt)
                #pragma unroll
                for (int ctl = 0; ctl < 4; ++ctl)
                    acc2[rt][ctl] = __builtin_amdgcn_mfma_f32_16x16x32_bf16(afr[rt], bfr[ctl], acc2[rt][ctl], 0, 0, 0);
        }
        __syncthreads();   // all h1 fragment reads done

        // write h2 = relu(acc2 + b2) over the same buffer
        #pragma unroll
        for (int rt = 0; rt < 4; ++rt)
            #pragma unroll
            for (int ctl = 0; ctl < 4; ++ctl)
                #pragma unroll
                for (int r = 0; r < 4; ++r) {
                    float g = fmaxf(acc2[rt][ctl][r] + b2v[ctl], 0.0f);
                    hs[(rt * 16 + 4 * lg + r) * HPITCH + (ct0 + ctl) * 16 + lr] = f2bf(g);
                }
        __syncthreads();

        // layer 3 via MFMA: wave w computes rows 16w..16w+15, logits in cols 0..2
        f32x4 acc3 = (f32x4){0.f, 0.f, 0.f, 0.f};
        for (int ks = 0; ks < KS2; ++ks) {
            bf16x8 afr = *(const bf16x8*)(hs + (16 * w + lr) * HPITCH + ks * 32 + 8 * lg);
            bf16x8 bfr = *(const bf16x8*)(W3p + ((size_t)(ks * 64 + lane)) * 8);
            acc3 = __builtin_amdgcn_mfma_f32_16x16x32_bf16(afr, bfr, acc3, 0, 0, 0);
        }
        if (lr < 3) {
            #pragma unroll
            for (int r = 0; r < 4; ++r)
                s_log[16 * w + 4 * lg + r][lr] = acc3[r];
        }
        __syncthreads();

        // softmax + write (one thread per pair-row)
        if (tid < BM && s_val[tid]) {
            float l0 = s_log[tid][0] + b30;
            float l1 = s_log[tid][1] + b31;
            float l2 = s_log[tid][2] + b32;
            float mx = fmaxf(l0, fmaxf(l1, l2));
            float e0 = expf(l0 - mx), e1 = expf(l1 - mx), e2 = expf(l2 - mx);
            float inv = 1.0f / (e0 + e1 + e2);
            float p0 = e0 * inv, p1 = e1 * inv, p2 = e2 * inv;
            size_t base = ((size_t)t * E + s_e[tid]) * 9;
            if (t == 0) {
                #pragma unroll
                for (int kb = 0; kb < 3; ++kb) {
                    cond[base + kb * 3 + 0] = p0;
                    cond[base + kb * 3 + 1] = p1;
                    cond[base + kb * 3 + 2] = p2;
                }
            } else {
                cond[base + k * 3 + 0] = p0;
                cond[base + k * 3 + 1] = p1;
                cond[base + k * 3 + 2] = p2;
            }
        }
    }
}

// ---------------------------------------------------------------------------
// Marginal chain: m_t = m_{t-1} @ cond[t]
// ---------------------------------------------------------------------------
__global__ __launch_bounds__(256)
void mfp_marg_kernel(const float* __restrict__ cond,
                     float* __restrict__ marg,
                     int E, int T)
{
    int e = blockIdx.x * 256 + threadIdx.x;
    if (e >= E) return;
    const float* c0 = &cond[(size_t)e * 9];
    float m0 = c0[0], m1 = c0[1], m2 = c0[2];
    marg[(size_t)e * 3 + 0] = m0;
    marg[(size_t)e * 3 + 1] = m1;
    marg[(size_t)e * 3 + 2] = m2;
    for (int t = 1; t <= T; ++t) {
        const float* c9 = &cond[((size_t)t * E + e) * 9];
        float n0 = m0 * c9[0] + m1 * c9[3] + m2 * c9[6];
        float n1 = m0 * c9[1] + m1 * c9[4] + m2 * c9[7];
        float n2 = m0 * c9[2] + m1 * c9[5] + m2 * c9[8];
        m0 = n0; m1 = n1; m2 = n2;
        float* mo = &marg[((size_t)t * E + e) * 3];
        mo[0] = m0; mo[1] = m1; mo[2] = m2;
    }
}

// ---------------------------------------------------------------------------
extern "C" void kernel_launch(void* const* d_in, const int* in_sizes, int n_in,
                              void* d_out, int out_size, void* d_ws, size_t ws_size,
                              hipStream_t stream) {
    const float* features  = (const float*)d_in[0];
    const float* states    = (const float*)d_in[1];
    const float* distances = (const float*)d_in[2];
    const float* W1 = (const float*)d_in[3];
    const float* b1 = (const float*)d_in[4];
    const float* W2 = (const float*)d_in[5];
    const float* b2 = (const float*)d_in[6];
    const float* W3 = (const float*)d_in[7];
    const float* b3 = (const float*)d_in[8];
    const int* pairs_i = (const int*)d_in[9];
    const int* pairs_j = (const int*)d_in[10];

    const int N   = in_sizes[0] / D_F;             // 2000
    const int T1s = in_sizes[1] / (N * 5);         // 11
    const int E   = in_sizes[9];                   // 100000
    const int T   = out_size / (12 * E) - 1;       // 10

    float* cond = (float*)d_out;                            // (T+1, E, 3, 3)
    float* marg = (float*)d_out + (size_t)(T + 1) * E * 9;  // (T+1, E, 3)

    u16* W1p = (u16*)d_ws;                                  // 16*KS1*64*8 elems
    u16* W2p = W1p + 16 * KS1 * 64 * 8;                     // 16*KS2*64*8 elems
    u16* W3p = W2p + 16 * KS2 * 64 * 8;                     // KS2*64*8 elems

    {
        int g1 = 16 * KS1 * 64;
        int g2 = 16 * KS2 * 64;
        int g3 = KS2 * 64;
        pack_w_kernel<<<(g1 + 255) / 256, 256, 0, stream>>>(W1, W1p, IN_F, KS1);
        pack_w_kernel<<<(g2 + 255) / 256, 256, 0, stream>>>(W2, W2p, HID, KS2);
        pack_w3_kernel<<<(g3 + 255) / 256, 256, 0, stream>>>(W3, W3p);
    }

    dim3 grid((E + BM - 1) / BM, T + 1);
    const size_t lds_bytes = (size_t)BM * HPITCH * sizeof(u16);   // 33792 B

    mfp_mlp_mfma<<<grid, 256, lds_bytes, stream>>>(
        features, states, distances, W1, W1p, b1, W2p, b2, W3p, b3,
        pairs_i, pairs_j, cond, N, T1s, E, T);

    mfp_marg_kernel<<<(E + 255) / 256, 256, 0, stream>>>(cond, marg, E, T);
}

// Round 6
// 1031.633 us; speedup vs baseline: 2.7149x; 1.3047x over previous
//
#include <hip/hip_runtime.h>
#include <hip/hip_bf16.h>
#include <math.h>

#define D_F   64
#define IN_F  183     // 2*64 + 2*25 + 3 + 1 + 1
#define KS1   6       // layer-1 K tiles: 192 = 6*32 (padded from 183)
#define KS2   8       // layer-2/3 K tiles: 256 = 8*32
#define HID   256
#define XPITCH 200    // u16 per x row: 400B; 400/16=25, 25%8==1 -> uniform bank spread
#define HPITCH 264    // u16 per h row: 528B; 528/16=33, 33%8==1
#define BM    64      // pairs per block
#define BLK   512     // 8 waves

typedef unsigned short u16;
typedef __attribute__((ext_vector_type(8))) short bf16x8;
typedef __attribute__((ext_vector_type(4))) float f32x4;

__device__ __forceinline__ u16 f2bf(float v) {
    __hip_bfloat16 h = __float2bfloat16(v);   // RNE
    u16 u; __builtin_memcpy(&u, &h, 2); return u;
}

// ---------------------------------------------------------------------------
// Pack W (K x 256 f32, row-major) into MFMA B-fragment order (bf16):
//   Wp[((ct*KSs + ks)*64 + lane)*8 + j] = W[ks*32 + 8*(lane>>4) + j][ct*16 + (lane&15)]
// ---------------------------------------------------------------------------
__global__ void pack_w_kernel(const float* __restrict__ W, u16* __restrict__ Wp,
                              int K, int KSs)
{
    int g = blockIdx.x * 256 + threadIdx.x;
    int total = 16 * KSs * 64;
    if (g >= total) return;
    int lane = g & 63;
    int ks   = (g >> 6) % KSs;
    int ct   = (g >> 6) / KSs;
    int col  = ct * 16 + (lane & 15);
    int kb   = ks * 32 + 8 * (lane >> 4);
    u16 out[8];
    #pragma unroll
    for (int j = 0; j < 8; ++j) {
        int k = kb + j;
        out[j] = f2bf((k < K) ? W[(size_t)k * HID + col] : 0.0f);
    }
    *(bf16x8*)(Wp + (size_t)g * 8) = *(const bf16x8*)out;
}

// Pack W3 (256 x 3 f32) into a 16-col B fragment (cols 3..15 zero)
__global__ void pack_w3_kernel(const float* __restrict__ W3, u16* __restrict__ W3p)
{
    int g = blockIdx.x * 256 + threadIdx.x;
    if (g >= KS2 * 64) return;
    int lane = g & 63;
    int ks   = g >> 6;
    int n    = lane & 15;
    int kb   = ks * 32 + 8 * (lane >> 4);
    u16 out[8];
    #pragma unroll
    for (int j = 0; j < 8; ++j)
        out[j] = f2bf((n < 3) ? W3[(size_t)(kb + j) * 3 + n] : 0.0f);
    *(bf16x8*)(W3p + (size_t)g * 8) = *(const bf16x8*)out;
}

// ---------------------------------------------------------------------------
// Pair-block fused MLP. Block = 64 pairs at one fixed t (gridDim.y = T+1),
// 512 threads = 8 waves; wave w owns all 64 rows x cols [32w, 32w+32).
// Thin tile: acc1[4][2]+acc2[4][2] = 64 VGPR -> target VGPR<=128 for 4 w/SIMD.
// Double-buffered LDS (h1 in A, h2 in B) -> 3 barriers per k.
// Softmax in-wave via shfl_xor on the layer-3 MFMA accumulator (no LDS stash).
// ---------------------------------------------------------------------------
__global__ __launch_bounds__(BLK)
void mfp_mlp_mfma(const float* __restrict__ features,
                  const float* __restrict__ states,
                  const float* __restrict__ distances,
                  const float* __restrict__ W1,   // f32, for one-hot rows 178..180
                  const u16* __restrict__ W1p, const float* __restrict__ b1,
                  const u16* __restrict__ W2p, const float* __restrict__ b2,
                  const u16* __restrict__ W3p, const float* __restrict__ b3,
                  const int* __restrict__ pairs_i, const int* __restrict__ pairs_j,
                  float* __restrict__ cond,
                  int N, int T1s, int E, int T)
{
    extern __shared__ char smem[];
    u16* hsA = (u16*)smem;               // [64][HPITCH]: x, then h1 per k
    u16* hsB = hsA + BM * HPITCH;        // [64][HPITCH]: h2 per k
    __shared__ int   s_pi[BM], s_pj[BM], s_e[BM], s_val[BM];
    __shared__ float s_dist[BM];

    const int tid = threadIdx.x;
    const int t   = blockIdx.y;
    const int nk  = (t == 0) ? 1 : 3;

    // ---- per-pair meta ----
    if (tid < BM) {
        int pe = blockIdx.x * BM + tid;
        int valid = (pe < E) ? 1 : 0;
        int e = valid ? pe : 0;
        int pi = pairs_i[e], pj = pairs_j[e];
        s_e[tid] = e; s_val[tid] = valid; s_pi[tid] = pi; s_pj[tid] = pj;
        s_dist[tid] = distances[(long long)pi * N + pj];
    }
    __syncthreads();

    // ---- assemble x rows (bf16) into hsA, one-hot cols (178..180) zeroed ----
    u16* xs = hsA;
    for (int idx = tid; idx < BM * 32; idx += BLK) {     // cols 0..127: features
        int m = idx >> 5;
        int q = idx & 31;
        int src = (q < 16) ? s_pi[m] : s_pj[m];
        int c4  = (q & 15) * 4;
        float4 f = *(const float4*)&features[(size_t)src * D_F + c4];
        int c = ((q < 16) ? 0 : 64) + c4;
        ushort4 o;
        o.x = f2bf(f.x); o.y = f2bf(f.y); o.z = f2bf(f.z); o.w = f2bf(f.w);
        *(ushort4*)(xs + m * XPITCH + c) = o;
    }
    for (int idx = tid; idx < BM * 64; idx += BLK) {     // cols 128..191
        int m = idx >> 6;
        int c = 128 + (idx & 63);
        float v;
        if (c < 178) {
            int cc = c - 128;
            int row = (cc < 25) ? s_pi[m] : s_pj[m];
            int c2  = (cc < 25) ? cc : (cc - 25);
            int l = c2 / 5;
            int s = c2 - l * 5;
            int tau = t - 4 + l;
            v = (tau >= 0) ? states[((size_t)row * T1s + tau) * 5 + s] : 0.0f;
        } else if (c == 181) {
            v = s_dist[m];
        } else if (c == 182) {
            v = (t == 0) ? 1.0f : 0.0f;
        } else {
            v = 0.0f;   // one-hot 178..180 and pad 183..191
        }
        xs[m * XPITCH + c] = f2bf(v);
    }
    __syncthreads();

    const int lane = tid & 63;
    const int w    = tid >> 6;     // wave id 0..7
    const int lr   = lane & 15;
    const int lg   = lane >> 4;
    // wave w owns col tiles ct = 2w, 2w+1  (cols 32w .. 32w+31)

    // ---- layer 1 (once): acc1 = x @ W1  (held across the k-loop) ----
    f32x4 acc1[4][2];
    #pragma unroll
    for (int a = 0; a < 4; ++a)
        #pragma unroll
        for (int b = 0; b < 2; ++b)
            acc1[a][b] = (f32x4){0.f, 0.f, 0.f, 0.f};

    for (int ks = 0; ks < KS1; ++ks) {
        bf16x8 bfr[2];
        #pragma unroll
        for (int cl = 0; cl < 2; ++cl)
            bfr[cl] = *(const bf16x8*)(W1p + (((size_t)(2 * w + cl) * KS1 + ks) * 64 + lane) * 8);
        bf16x8 afr[4];
        #pragma unroll
        for (int rt = 0; rt < 4; ++rt)
            afr[rt] = *(const bf16x8*)(xs + (rt * 16 + lr) * XPITCH + ks * 32 + 8 * lg);
        #pragma unroll
        for (int rt = 0; rt < 4; ++rt)
            #pragma unroll
            for (int cl = 0; cl < 2; ++cl)
                acc1[rt][cl] = __builtin_amdgcn_mfma_f32_16x16x32_bf16(afr[rt], bfr[cl], acc1[rt][cl], 0, 0, 0);
    }

    // per-lane column constants
    float b1v[2], b2v[2], w1oh[3][2];
    #pragma unroll
    for (int cl = 0; cl < 2; ++cl) {
        int col = (2 * w + cl) * 16 + lr;
        b1v[cl] = b1[col];
        b2v[cl] = b2[col];
        #pragma unroll
        for (int k3 = 0; k3 < 3; ++k3)
            w1oh[k3][cl] = W1[(size_t)(178 + k3) * HID + col];
    }
    const float b30 = b3[0], b31 = b3[1], b32 = b3[2];

    // ---- k-loop (3 barriers per k) ----
    for (int k = 0; k < nk; ++k) {
        __syncthreads();   // A's readers done (x reads at k=0, L2 reads at k>0)

        // h1_k = relu(acc1 + b1 + W1[178+k]) -> hsA
        #pragma unroll
        for (int rt = 0; rt < 4; ++rt)
            #pragma unroll
            for (int cl = 0; cl < 2; ++cl)
                #pragma unroll
                for (int r = 0; r < 4; ++r) {
                    float h = fmaxf(acc1[rt][cl][r] + b1v[cl] + w1oh[k][cl], 0.0f);
                    hsA[(rt * 16 + 4 * lg + r) * HPITCH + (2 * w + cl) * 16 + lr] = f2bf(h);
                }
        __syncthreads();   // h1 ready

        // layer 2: acc2 = h1 @ W2
        f32x4 acc2[4][2];
        #pragma unroll
        for (int a = 0; a < 4; ++a)
            #pragma unroll
            for (int b = 0; b < 2; ++b)
                acc2[a][b] = (f32x4){0.f, 0.f, 0.f, 0.f};

        for (int ks = 0; ks < KS2; ++ks) {
            bf16x8 bfr[2];
            #pragma unroll
            for (int cl = 0; cl < 2; ++cl)
                bfr[cl] = *(const bf16x8*)(W2p + (((size_t)(2 * w + cl) * KS2 + ks) * 64 + lane) * 8);
            bf16x8 afr[4];
            #pragma unroll
            for (int rt = 0; rt < 4; ++rt)
                afr[rt] = *(const bf16x8*)(hsA + (rt * 16 + lr) * HPITCH + ks * 32 + 8 * lg);
            #pragma unroll
            for (int rt = 0; rt < 4; ++rt)
                #pragma unroll
                for (int cl = 0; cl < 2; ++cl)
                    acc2[rt][cl] = __builtin_amdgcn_mfma_f32_16x16x32_bf16(afr[rt], bfr[cl], acc2[rt][cl], 0, 0, 0);
        }

        // h2 = relu(acc2 + b2) -> hsB  (different buffer: no barrier needed here)
        #pragma unroll
        for (int rt = 0; rt < 4; ++rt)
            #pragma unroll
            for (int cl = 0; cl < 2; ++cl)
                #pragma unroll
                for (int r = 0; r < 4; ++r) {
                    float g = fmaxf(acc2[rt][cl][r] + b2v[cl], 0.0f);
                    hsB[(rt * 16 + 4 * lg + r) * HPITCH + (2 * w + cl) * 16 + lr] = f2bf(g);
                }
        __syncthreads();   // h2 ready

        // layer 3 via MFMA on waves 0..3: wave w -> rows 16w..16w+15
        if (w < 4) {
            f32x4 acc3 = (f32x4){0.f, 0.f, 0.f, 0.f};
            for (int ks = 0; ks < KS2; ++ks) {
                bf16x8 afr = *(const bf16x8*)(hsB + (16 * w + lr) * HPITCH + ks * 32 + 8 * lg);
                bf16x8 bfr = *(const bf16x8*)(W3p + ((size_t)(ks * 64 + lane)) * 8);
                acc3 = __builtin_amdgcn_mfma_f32_16x16x32_bf16(afr, bfr, acc3, 0, 0, 0);
            }
            // lane lr holds logit col lr of rows 16w+4lg+r; gather cols 1,2 via shfl
            #pragma unroll
            for (int r = 0; r < 4; ++r) {
                float l0 = acc3[r];
                float l1 = __shfl_xor(acc3[r], 1, 64);
                float l2 = __shfl_xor(acc3[r], 2, 64);
                int m = 16 * w + 4 * lg + r;
                if (lr == 0 && s_val[m]) {
                    l0 += b30; l1 += b31; l2 += b32;
                    float mx = fmaxf(l0, fmaxf(l1, l2));
                    float e0 = expf(l0 - mx), e1 = expf(l1 - mx), e2 = expf(l2 - mx);
                    float inv = 1.0f / (e0 + e1 + e2);
                    float p0 = e0 * inv, p1 = e1 * inv, p2 = e2 * inv;
                    size_t base = ((size_t)t * E + s_e[m]) * 9;
                    if (t == 0) {
                        #pragma unroll
                        for (int kb = 0; kb < 3; ++kb) {
                            cond[base + kb * 3 + 0] = p0;
                            cond[base + kb * 3 + 1] = p1;
                            cond[base + kb * 3 + 2] = p2;
                        }
                    } else {
                        cond[base + k * 3 + 0] = p0;
                        cond[base + k * 3 + 1] = p1;
                        cond[base + k * 3 + 2] = p2;
                    }
                }
            }
        }
    }
}

// ---------------------------------------------------------------------------
// Marginal chain: m_t = m_{t-1} @ cond[t]
// ---------------------------------------------------------------------------
__global__ __launch_bounds__(256)
void mfp_marg_kernel(const float* __restrict__ cond,
                     float* __restrict__ marg,
                     int E, int T)
{
    int e = blockIdx.x * 256 + threadIdx.x;
    if (e >= E) return;
    const float* c0 = &cond[(size_t)e * 9];
    float m0 = c0[0], m1 = c0[1], m2 = c0[2];
    marg[(size_t)e * 3 + 0] = m0;
    marg[(size_t)e * 3 + 1] = m1;
    marg[(size_t)e * 3 + 2] = m2;
    for (int t = 1; t <= T; ++t) {
        const float* c9 = &cond[((size_t)t * E + e) * 9];
        float n0 = m0 * c9[0] + m1 * c9[3] + m2 * c9[6];
        float n1 = m0 * c9[1] + m1 * c9[4] + m2 * c9[7];
        float n2 = m0 * c9[2] + m1 * c9[5] + m2 * c9[8];
        m0 = n0; m1 = n1; m2 = n2;
        float* mo = &marg[((size_t)t * E + e) * 3];
        mo[0] = m0; mo[1] = m1; mo[2] = m2;
    }
}

// ---------------------------------------------------------------------------
extern "C" void kernel_launch(void* const* d_in, const int* in_sizes, int n_in,
                              void* d_out, int out_size, void* d_ws, size_t ws_size,
                              hipStream_t stream) {
    const float* features  = (const float*)d_in[0];
    const float* states    = (const float*)d_in[1];
    const float* distances = (const float*)d_in[2];
    const float* W1 = (const float*)d_in[3];
    const float* b1 = (const float*)d_in[4];
    const float* W2 = (const float*)d_in[5];
    const float* b2 = (const float*)d_in[6];
    const float* W3 = (const float*)d_in[7];
    const float* b3 = (const float*)d_in[8];
    const int* pairs_i = (const int*)d_in[9];
    const int* pairs_j = (const int*)d_in[10];

    const int N   = in_sizes[0] / D_F;             // 2000
    const int T1s = in_sizes[1] / (N * 5);         // 11
    const int E   = in_sizes[9];                   // 100000
    const int T   = out_size / (12 * E) - 1;       // 10

    float* cond = (float*)d_out;                            // (T+1, E, 3, 3)
    float* marg = (float*)d_out + (size_t)(T + 1) * E * 9;  // (T+1, E, 3)

    u16* W1p = (u16*)d_ws;                                  // 16*KS1*64*8 elems
    u16* W2p = W1p + 16 * KS1 * 64 * 8;                     // 16*KS2*64*8 elems
    u16* W3p = W2p + 16 * KS2 * 64 * 8;                     // KS2*64*8 elems

    {
        int g1 = 16 * KS1 * 64;
        int g2 = 16 * KS2 * 64;
        int g3 = KS2 * 64;
        pack_w_kernel<<<(g1 + 255) / 256, 256, 0, stream>>>(W1, W1p, IN_F, KS1);
        pack_w_kernel<<<(g2 + 255) / 256, 256, 0, stream>>>(W2, W2p, HID, KS2);
        pack_w3_kernel<<<(g3 + 255) / 256, 256, 0, stream>>>(W3, W3p);
    }

    dim3 grid((E + BM - 1) / BM, T + 1);
    const size_t lds_bytes = (size_t)2 * BM * HPITCH * sizeof(u16);   // 67584 B

    mfp_mlp_mfma<<<grid, BLK, lds_bytes, stream>>>(
        features, states, distances, W1, W1p, b1, W2p, b2, W3p, b3,
        pairs_i, pairs_j, cond, N, T1s, E, T);

    mfp_marg_kernel<<<(E + 255) / 256, 256, 0, stream>>>(cond, marg, E, T);
}

// Round 7
// 886.834 us; speedup vs baseline: 3.1582x; 1.1633x over previous
//
#include <hip/hip_runtime.h>
#include <hip/hip_bf16.h>
#include <math.h>

#define D_F   64
#define IN_F  183     // 2*64 + 2*25 + 3 + 1 + 1
#define KS1   6       // layer-1 K tiles: 192 = 6*32 (padded from 183)
#define KS2   8       // layer-2/3 K tiles: 256 = 8*32
#define HID   256
#define HPITCH 264    // u16 per row: 528B; 528/16=33, 33%8==1 -> uniform bank spread
#define BM    64      // pairs per block
#define BLK   512     // 8 waves

typedef unsigned short u16;
typedef __attribute__((ext_vector_type(8))) short bf16x8;
typedef __attribute__((ext_vector_type(4))) float f32x4;

__device__ __forceinline__ u16 f2bf(float v) {
    __hip_bfloat16 h = __float2bfloat16(v);   // RNE
    u16 u; __builtin_memcpy(&u, &h, 2); return u;
}

// ---------------------------------------------------------------------------
// Pack W (K x 256 f32, row-major) into MFMA fragment order (bf16):
//   Wp[((ct*KSs + ks)*64 + lane)*8 + j] = W[ks*32 + 8*(lane>>4) + j][ct*16 + (lane&15)]
// This layout serves as A-operand (row = lane&15 = hidden col of W^T) in the
// transposed scheme; identical to the old B-operand packing.
// ---------------------------------------------------------------------------
__global__ void pack_w_kernel(const float* __restrict__ W, u16* __restrict__ Wp,
                              int K, int KSs)
{
    int g = blockIdx.x * 256 + threadIdx.x;
    int total = 16 * KSs * 64;
    if (g >= total) return;
    int lane = g & 63;
    int ks   = (g >> 6) % KSs;
    int ct   = (g >> 6) / KSs;
    int col  = ct * 16 + (lane & 15);
    int kb   = ks * 32 + 8 * (lane >> 4);
    u16 out[8];
    #pragma unroll
    for (int j = 0; j < 8; ++j) {
        int k = kb + j;
        out[j] = f2bf((k < K) ? W[(size_t)k * HID + col] : 0.0f);
    }
    *(bf16x8*)(Wp + (size_t)g * 8) = *(const bf16x8*)out;
}

// Pack W3 (256 x 3 f32): rows n<3 of W3^T, rest zero
__global__ void pack_w3_kernel(const float* __restrict__ W3, u16* __restrict__ W3p)
{
    int g = blockIdx.x * 256 + threadIdx.x;
    if (g >= KS2 * 64) return;
    int lane = g & 63;
    int ks   = g >> 6;
    int n    = lane & 15;
    int kb   = ks * 32 + 8 * (lane >> 4);
    u16 out[8];
    #pragma unroll
    for (int j = 0; j < 8; ++j)
        out[j] = f2bf((n < 3) ? W3[(size_t)(kb + j) * 3 + n] : 0.0f);
    *(bf16x8*)(W3p + (size_t)g * 8) = *(const bf16x8*)out;
}

// ---------------------------------------------------------------------------
// Transposed pair-block fused MLP. Block = 64 pairs at one t (gridDim.y=T+1),
// 512 threads = 8 waves. All GEMMs computed transposed: D = W^T . x^T, so
// D[row=hidden][col=pair]. Wave w owns hidden tiles {2w,2w+1} x all 4 pair
// tiles. Lane then holds 4 CONSECUTIVE hidden dims of one pair -> epilogue is
// 8 x ds_write_b64 (vs 32 x b16 in the row-major scheme), and layer-3's
// output lane (lg==0) holds all 3 logits of one pair -> shuffle-free softmax.
// Single 33.8KB LDS buffer (x -> h1 -> h2), 4 barriers per k.
// VGPR budget: acc1[2][4]+acc2[2][4]=64 + frags ~32 + misc -> target <=128
// for 4 waves/SIMD (2 blocks/CU). No min-waves bound (round-4 spill lesson).
// ---------------------------------------------------------------------------
__global__ __launch_bounds__(BLK)
void mfp_mlp_mfma(const float* __restrict__ features,
                  const float* __restrict__ states,
                  const float* __restrict__ distances,
                  const float* __restrict__ W1,   // f32, for one-hot rows 178..180
                  const u16* __restrict__ W1p, const float* __restrict__ b1,
                  const u16* __restrict__ W2p, const float* __restrict__ b2,
                  const u16* __restrict__ W3p, const float* __restrict__ b3,
                  const int* __restrict__ pairs_i, const int* __restrict__ pairs_j,
                  float* __restrict__ cond,
                  int N, int T1s, int E, int T)
{
    extern __shared__ char smem[];
    u16* hsA = (u16*)smem;               // [64][HPITCH]: x, then h1, then h2
    __shared__ int   s_pi[BM], s_pj[BM], s_e[BM], s_val[BM];
    __shared__ float s_dist[BM];

    const int tid = threadIdx.x;
    const int t   = blockIdx.y;
    const int nk  = (t == 0) ? 1 : 3;

    // ---- per-pair meta ----
    if (tid < BM) {
        int pe = blockIdx.x * BM + tid;
        int valid = (pe < E) ? 1 : 0;
        int e = valid ? pe : 0;
        int pi = pairs_i[e], pj = pairs_j[e];
        s_e[tid] = e; s_val[tid] = valid; s_pi[tid] = pi; s_pj[tid] = pj;
        s_dist[tid] = distances[(long long)pi * N + pj];
    }
    __syncthreads();

    // ---- assemble x rows (bf16) into hsA, one-hot cols (178..180) zeroed ----
    u16* xs = hsA;
    for (int idx = tid; idx < BM * 32; idx += BLK) {     // cols 0..127: features
        int m = idx >> 5;
        int q = idx & 31;
        int src = (q < 16) ? s_pi[m] : s_pj[m];
        int c4  = (q & 15) * 4;
        float4 f = *(const float4*)&features[(size_t)src * D_F + c4];
        int c = ((q < 16) ? 0 : 64) + c4;
        ushort4 o;
        o.x = f2bf(f.x); o.y = f2bf(f.y); o.z = f2bf(f.z); o.w = f2bf(f.w);
        *(ushort4*)(xs + m * HPITCH + c) = o;
    }
    for (int idx = tid; idx < BM * 64; idx += BLK) {     // cols 128..191
        int m = idx >> 6;
        int c = 128 + (idx & 63);
        float v;
        if (c < 178) {
            int cc = c - 128;
            int row = (cc < 25) ? s_pi[m] : s_pj[m];
            int c2  = (cc < 25) ? cc : (cc - 25);
            int l = c2 / 5;
            int s = c2 - l * 5;
            int tau = t - 4 + l;
            v = (tau >= 0) ? states[((size_t)row * T1s + tau) * 5 + s] : 0.0f;
        } else if (c == 181) {
            v = s_dist[m];
        } else if (c == 182) {
            v = (t == 0) ? 1.0f : 0.0f;
        } else {
            v = 0.0f;   // one-hot 178..180 and pad 183..191
        }
        xs[m * HPITCH + c] = f2bf(v);
    }
    __syncthreads();

    const int lane = tid & 63;
    const int w    = tid >> 6;     // wave id 0..7
    const int lr   = lane & 15;
    const int lg   = lane >> 4;
    // wave w owns hidden tiles mt = 2w, 2w+1 (hidden dims 32w .. 32w+31)

    // ---- layer 1 (once): acc1 = W1^T . x^T  (held across the k-loop) ----
    // D[row = hidden h][col = pair m]; lane: m = 16nt+lr, h = 16mt+4lg+r
    f32x4 acc1[2][4];   // [mtl][nt]
    #pragma unroll
    for (int a = 0; a < 2; ++a)
        #pragma unroll
        for (int b = 0; b < 4; ++b)
            acc1[a][b] = (f32x4){0.f, 0.f, 0.f, 0.f};

    for (int ks = 0; ks < KS1; ++ks) {
        bf16x8 wfr[2];
        #pragma unroll
        for (int mtl = 0; mtl < 2; ++mtl)
            wfr[mtl] = *(const bf16x8*)(W1p + (((size_t)(2 * w + mtl) * KS1 + ks) * 64 + lane) * 8);
        bf16x8 xfr[4];
        #pragma unroll
        for (int nt = 0; nt < 4; ++nt)
            xfr[nt] = *(const bf16x8*)(xs + (nt * 16 + lr) * HPITCH + ks * 32 + 8 * lg);
        #pragma unroll
        for (int mtl = 0; mtl < 2; ++mtl)
            #pragma unroll
            for (int nt = 0; nt < 4; ++nt)
                acc1[mtl][nt] = __builtin_amdgcn_mfma_f32_16x16x32_bf16(wfr[mtl], xfr[nt], acc1[mtl][nt], 0, 0, 0);
    }

    // per-lane hidden-dim constants: h = 16*(2w+mtl) + 4*lg + r, r=0..3
    f32x4 b1q[2], b2q[2];
    #pragma unroll
    for (int mtl = 0; mtl < 2; ++mtl) {
        int h0 = 16 * (2 * w + mtl) + 4 * lg;
        b1q[mtl] = *(const f32x4*)&b1[h0];
        b2q[mtl] = *(const f32x4*)&b2[h0];
    }
    const float b30 = b3[0], b31 = b3[1], b32 = b3[2];

    // ---- k-loop (4 barriers per k) ----
    for (int k = 0; k < nk; ++k) {
        // one-hot row contribution for this k (reloaded per k to save VGPRs)
        f32x4 ohq[2];
        #pragma unroll
        for (int mtl = 0; mtl < 2; ++mtl)
            ohq[mtl] = *(const f32x4*)&W1[(size_t)(178 + k) * HID + 16 * (2 * w + mtl) + 4 * lg];

        __syncthreads();   // x reads (k=0) / prev k's layer-3 reads done

        // h1_k = relu(acc1 + b1 + W1[178+k]) -> hsA[m][h], b64 stores
        #pragma unroll
        for (int mtl = 0; mtl < 2; ++mtl)
            #pragma unroll
            for (int nt = 0; nt < 4; ++nt) {
                ushort4 p;
                p.x = f2bf(fmaxf(acc1[mtl][nt][0] + b1q[mtl][0] + ohq[mtl][0], 0.0f));
                p.y = f2bf(fmaxf(acc1[mtl][nt][1] + b1q[mtl][1] + ohq[mtl][1], 0.0f));
                p.z = f2bf(fmaxf(acc1[mtl][nt][2] + b1q[mtl][2] + ohq[mtl][2], 0.0f));
                p.w = f2bf(fmaxf(acc1[mtl][nt][3] + b1q[mtl][3] + ohq[mtl][3], 0.0f));
                *(ushort4*)(hsA + (nt * 16 + lr) * HPITCH + 16 * (2 * w + mtl) + 4 * lg) = p;
            }
        __syncthreads();   // h1 ready

        // layer 2: acc2 = W2^T . h1^T
        f32x4 acc2[2][4];
        #pragma unroll
        for (int a = 0; a < 2; ++a)
            #pragma unroll
            for (int b = 0; b < 4; ++b)
                acc2[a][b] = (f32x4){0.f, 0.f, 0.f, 0.f};

        for (int ks = 0; ks < KS2; ++ks) {
            bf16x8 wfr[2];
            #pragma unroll
            for (int mtl = 0; mtl < 2; ++mtl)
                wfr[mtl] = *(const bf16x8*)(W2p + (((size_t)(2 * w + mtl) * KS2 + ks) * 64 + lane) * 8);
            bf16x8 hfr[4];
            #pragma unroll
            for (int nt = 0; nt < 4; ++nt)
                hfr[nt] = *(const bf16x8*)(hsA + (nt * 16 + lr) * HPITCH + ks * 32 + 8 * lg);
            #pragma unroll
            for (int mtl = 0; mtl < 2; ++mtl)
                #pragma unroll
                for (int nt = 0; nt < 4; ++nt)
                    acc2[mtl][nt] = __builtin_amdgcn_mfma_f32_16x16x32_bf16(wfr[mtl], hfr[nt], acc2[mtl][nt], 0, 0, 0);
        }
        __syncthreads();   // all h1 reads done; safe to overwrite with h2

        // h2 = relu(acc2 + b2) -> hsA[m][h], b64 stores
        #pragma unroll
        for (int mtl = 0; mtl < 2; ++mtl)
            #pragma unroll
            for (int nt = 0; nt < 4; ++nt) {
                ushort4 p;
                p.x = f2bf(fmaxf(acc2[mtl][nt][0] + b2q[mtl][0], 0.0f));
                p.y = f2bf(fmaxf(acc2[mtl][nt][1] + b2q[mtl][1], 0.0f));
                p.z = f2bf(fmaxf(acc2[mtl][nt][2] + b2q[mtl][2], 0.0f));
                p.w = f2bf(fmaxf(acc2[mtl][nt][3] + b2q[mtl][3], 0.0f));
                *(ushort4*)(hsA + (nt * 16 + lr) * HPITCH + 16 * (2 * w + mtl) + 4 * lg) = p;
            }
        __syncthreads();   // h2 ready

        // layer 3: logits^T = W3^T . h2^T, waves 0..3, wave w -> pairs 16w..16w+15
        if (w < 4) {
            f32x4 acc3 = (f32x4){0.f, 0.f, 0.f, 0.f};
            for (int ks = 0; ks < KS2; ++ks) {
                bf16x8 hfr = *(const bf16x8*)(hsA + (w * 16 + lr) * HPITCH + ks * 32 + 8 * lg);
                bf16x8 wfr = *(const bf16x8*)(W3p + ((size_t)(ks * 64 + lane)) * 8);
                acc3 = __builtin_amdgcn_mfma_f32_16x16x32_bf16(wfr, hfr, acc3, 0, 0, 0);
            }
            // lane (lg==0, lr): acc3[r] = logit n=r of pair m = 16w+lr
            int m = 16 * w + lr;
            if (lg == 0 && s_val[m]) {
                float l0 = acc3[0] + b30;
                float l1 = acc3[1] + b31;
                float l2 = acc3[2] + b32;
                float mx = fmaxf(l0, fmaxf(l1, l2));
                float e0 = expf(l0 - mx), e1 = expf(l1 - mx), e2 = expf(l2 - mx);
                float inv = 1.0f / (e0 + e1 + e2);
                float p0 = e0 * inv, p1 = e1 * inv, p2 = e2 * inv;
                size_t base = ((size_t)t * E + s_e[m]) * 9;
                if (t == 0) {
                    #pragma unroll
                    for (int kb = 0; kb < 3; ++kb) {
                        cond[base + kb * 3 + 0] = p0;
                        cond[base + kb * 3 + 1] = p1;
                        cond[base + kb * 3 + 2] = p2;
                    }
                } else {
                    cond[base + k * 3 + 0] = p0;
                    cond[base + k * 3 + 1] = p1;
                    cond[base + k * 3 + 2] = p2;
                }
            }
        }
    }
}

// ---------------------------------------------------------------------------
// Marginal chain: m_t = m_{t-1} @ cond[t]
// ---------------------------------------------------------------------------
__global__ __launch_bounds__(256)
void mfp_marg_kernel(const float* __restrict__ cond,
                     float* __restrict__ marg,
                     int E, int T)
{
    int e = blockIdx.x * 256 + threadIdx.x;
    if (e >= E) return;
    const float* c0 = &cond[(size_t)e * 9];
    float m0 = c0[0], m1 = c0[1], m2 = c0[2];
    marg[(size_t)e * 3 + 0] = m0;
    marg[(size_t)e * 3 + 1] = m1;
    marg[(size_t)e * 3 + 2] = m2;
    for (int t = 1; t <= T; ++t) {
        const float* c9 = &cond[((size_t)t * E + e) * 9];
        float n0 = m0 * c9[0] + m1 * c9[3] + m2 * c9[6];
        float n1 = m0 * c9[1] + m1 * c9[4] + m2 * c9[7];
        float n2 = m0 * c9[2] + m1 * c9[5] + m2 * c9[8];
        m0 = n0; m1 = n1; m2 = n2;
        float* mo = &marg[((size_t)t * E + e) * 3];
        mo[0] = m0; mo[1] = m1; mo[2] = m2;
    }
}

// ---------------------------------------------------------------------------
extern "C" void kernel_launch(void* const* d_in, const int* in_sizes, int n_in,
                              void* d_out, int out_size, void* d_ws, size_t ws_size,
                              hipStream_t stream) {
    const float* features  = (const float*)d_in[0];
    const float* states    = (const float*)d_in[1];
    const float* distances = (const float*)d_in[2];
    const float* W1 = (const float*)d_in[3];
    const float* b1 = (const float*)d_in[4];
    const float* W2 = (const float*)d_in[5];
    const float* b2 = (const float*)d_in[6];
    const float* W3 = (const float*)d_in[7];
    const float* b3 = (const float*)d_in[8];
    const int* pairs_i = (const int*)d_in[9];
    const int* pairs_j = (const int*)d_in[10];

    const int N   = in_sizes[0] / D_F;             // 2000
    const int T1s = in_sizes[1] / (N * 5);         // 11
    const int E   = in_sizes[9];                   // 100000
    const int T   = out_size / (12 * E) - 1;       // 10

    float* cond = (float*)d_out;                            // (T+1, E, 3, 3)
    float* marg = (float*)d_out + (size_t)(T + 1) * E * 9;  // (T+1, E, 3)

    u16* W1p = (u16*)d_ws;                                  // 16*KS1*64*8 elems
    u16* W2p = W1p + 16 * KS1 * 64 * 8;                     // 16*KS2*64*8 elems
    u16* W3p = W2p + 16 * KS2 * 64 * 8;                     // KS2*64*8 elems

    {
        int g1 = 16 * KS1 * 64;
        int g2 = 16 * KS2 * 64;
        int g3 = KS2 * 64;
        pack_w_kernel<<<(g1 + 255) / 256, 256, 0, stream>>>(W1, W1p, IN_F, KS1);
        pack_w_kernel<<<(g2 + 255) / 256, 256, 0, stream>>>(W2, W2p, HID, KS2);
        pack_w3_kernel<<<(g3 + 255) / 256, 256, 0, stream>>>(W3, W3p);
    }

    dim3 grid((E + BM - 1) / BM, T + 1);
    const size_t lds_bytes = (size_t)BM * HPITCH * sizeof(u16);   // 33792 B

    mfp_mlp_mfma<<<grid, BLK, lds_bytes, stream>>>(
        features, states, distances, W1, W1p, b1, W2p, b2, W3p, b3,
        pairs_i, pairs_j, cond, N, T1s, E, T);

    mfp_marg_kernel<<<(E + 255) / 256, 256, 0, stream>>>(cond, marg, E, T);
}